// Round 13
// baseline (146.478 us; speedup 1.0000x reference)
//
#include <hip/hip_runtime.h>
#include <hip/hip_bf16.h>
#include <stdint.h>

#define T_SEQ 2048
#define DIMSZ 1024
#define NH    16
#define HDIM  64
#define NBATCH 2
#define KVB   64
#define ATT_SCALE 0.12f
#define QSCALE (0.12f * 1.4426950408889634f)

typedef __attribute__((ext_vector_type(8))) __bf16 bf16x8;
typedef __attribute__((ext_vector_type(8))) ushort u16x8;
typedef __attribute__((ext_vector_type(4))) float f32x4;

#define GLOAD_LDS16(gp, lp)                                                            \
  __builtin_amdgcn_global_load_lds((const __attribute__((address_space(1))) void*)(gp),\
                                   (__attribute__((address_space(3))) void*)(lp),      \
                                   16, 0, 0)

__device__ __forceinline__ ushort f2bf(float f) {
  union { float f; uint32_t u; } v; v.f = f;
  uint32_t u = v.u;
  uint32_t r = (u + 0x7FFFu + ((u >> 16) & 1u)) >> 16;
  return (ushort)r;
}

__device__ __forceinline__ float bf2f(ushort h) {
  union { float f; uint32_t u; } v;
  v.u = ((uint32_t)h) << 16;
  return v.f;
}

// paired f32->bf16 (compiler fuses into v_cvt_pk_bf16_f32)
__device__ __forceinline__ uint32_t pk2(float a, float b) {
  union { __hip_bfloat162 h; uint32_t u; } cv;
  cv.h = __hip_bfloat162(__float2bfloat16(a), __float2bfloat16(b));
  return cv.u;
}

// ---------------- f32 -> bf16 convert (vectorized) ----------------
__global__ __launch_bounds__(256) void conv_bf16_k(const float* __restrict__ in,
                                                   ushort* __restrict__ out, int n) {
  int i = (blockIdx.x * 256 + threadIdx.x) * 4;
  if (i >= n) return;
  float4 v = *(const float4*)(in + i);
  ushort4 o;
  o.x = f2bf(v.x); o.y = f2bf(v.y); o.z = f2bf(v.z); o.w = f2bf(v.w);
  *(ushort4*)(out + i) = o;
}

// ---------------- RoPE tables: cos/sin (T x 32) ----------------
__global__ __launch_bounds__(256) void rope_tab_k(float* __restrict__ ctab,
                                                  float* __restrict__ stab) {
  int idx = blockIdx.x * 256 + threadIdx.x;  // t*32 + j
  if (idx >= T_SEQ * 32) return;
  int j = idx & 31, t = idx >> 5;
  float c = 1.f, s = 0.f;
  if (j < 16) {
    float inv = powf(1024.0f, -(float)j / 15.0f);  // (1/1024)^(j/15)
    float th = (float)t * inv;
    c = cosf(th);
    s = sinf(th);
  }
  ctab[idx] = c;
  stab[idx] = s;
}

// ---------------- bf16 GEMM 128^2 (out-projection) ----------------
#define BM 128
#define BN 128
#define BKS 64

template <typename OT>
__global__ __launch_bounds__(256) void gemm_bt_k(const ushort* __restrict__ A,
                                                 const ushort* __restrict__ Bt,
                                                 OT* __restrict__ C,
                                                 int M, int N, int K) {
  __shared__ __align__(16) ushort As[BM * BKS];
  __shared__ __align__(16) ushort Bs[BN * BKS];
  int tid = threadIdx.x;
  int wave = tid >> 6, lane = tid & 63;
  int lr = lane & 15, lg = lane >> 4;
  int m0 = blockIdx.x * BM, n0 = blockIdx.y * BN;
  int wm = (wave >> 1) * 64, wn = (wave & 1) * 64;

  f32x4 acc[4][4];
  for (int m = 0; m < 4; ++m)
    for (int n = 0; n < 4; ++n)
      acc[m][n] = (f32x4){0.f, 0.f, 0.f, 0.f};

  for (int k0 = 0; k0 < K; k0 += BKS) {
#pragma unroll
    for (int it = 0; it < 4; ++it) {
      int idx = it * 256 + tid;        // 16B chunk id, 1024 total
      int row = idx >> 3;              // 8 chunks per 64-elem row
      int col = (idx & 7) * 8;
      GLOAD_LDS16(A + (size_t)(m0 + row) * K + k0 + col, &As[idx * 8]);
      GLOAD_LDS16(Bt + (size_t)(n0 + row) * K + k0 + col, &Bs[idx * 8]);
    }
    __syncthreads();
#pragma unroll
    for (int kk = 0; kk < 2; ++kk) {
      bf16x8 af[4], bf[4];
#pragma unroll
      for (int m = 0; m < 4; ++m)
        af[m] = *(const bf16x8*)&As[(wm + m * 16 + lr) * BKS + kk * 32 + lg * 8];
#pragma unroll
      for (int n = 0; n < 4; ++n)
        bf[n] = *(const bf16x8*)&Bs[(wn + n * 16 + lr) * BKS + kk * 32 + lg * 8];
#pragma unroll
      for (int m = 0; m < 4; ++m)
#pragma unroll
        for (int n = 0; n < 4; ++n)
          acc[m][n] = __builtin_amdgcn_mfma_f32_16x16x32_bf16(af[m], bf[n], acc[m][n], 0, 0, 0);
    }
    __syncthreads();
  }
#pragma unroll
  for (int m = 0; m < 4; ++m)
#pragma unroll
    for (int n = 0; n < 4; ++n)
#pragma unroll
      for (int r = 0; r < 4; ++r) {
        int row = m0 + wm + m * 16 + lg * 4 + r;
        int col = n0 + wn + n * 16 + lr;
        if constexpr (sizeof(OT) == 2)
          C[(size_t)row * N + col] = (OT)f2bf(acc[m][n][r]);
        else
          C[(size_t)row * N + col] = (OT)acc[m][n][r];
      }
}

// ---------------- QKV GEMM: 256^2, 8-phase schedule with derived waits ----------------
// T3+T4+T2+T5 co-designed (guide §5.5 dependency graph). Per K-tile, 4 phases:
// {vmcnt(w_p); s_barrier; fence; issue 2 next-tile 64-row units; ds_read A-quad_p
// (+ B-all at ph0 into regs); setprio(1); 16 MFMA; setprio(0)}.
// Stage stream/tile: ph0{Bu0,Bu1} ph1{Bu2,Bu3} ph2{Au0,Au2} ph3{Au1,Au3}; FIFO-derived
// waits: ph0 vmcnt(2) (worst-need Au2^T, 2 younger), ph2 vmcnt(4) (Au3^T, 4 younger);
// tail tile ph2 vmcnt(0). Next-tile loads stay in flight across up to 4 barriers.
// Issue-after-barrier makes buffer WAR provably safe (readers passed lgkmcnt(0) pre-MFMA).
#define BM2 256
#define BN2 256

#define QUAD(p)                                                                        \
  {                                                                                    \
    bf16x8 af[2][2];                                                                   \
    _Pragma("unroll") for (int i = 0; i < 2; ++i)                                      \
      _Pragma("unroll") for (int kk = 0; kk < 2; ++kk)                                 \
        af[i][kk] = *(const bf16x8*)&Ac[(wm + (2 * (p) + i) * 16 + lr) * 64 +          \
                                        (((kk * 4 + lg) ^ rs) << 3)];                  \
    __builtin_amdgcn_s_setprio(1);                                                     \
    _Pragma("unroll") for (int i = 0; i < 2; ++i)                                      \
      _Pragma("unroll") for (int kk = 0; kk < 2; ++kk)                                 \
        _Pragma("unroll") for (int n = 0; n < 4; ++n)                                  \
          acc[2 * (p) + i][n] = __builtin_amdgcn_mfma_f32_16x16x32_bf16(               \
              af[i][kk], bfr[n][kk], acc[2 * (p) + i][n], 0, 0, 0);                    \
    __builtin_amdgcn_s_setprio(0);                                                     \
  }

__global__ __launch_bounds__(512, 2) void gemm_qkv_k(const ushort* __restrict__ A,
                                                     const ushort* __restrict__ Bt,
                                                     const float* __restrict__ ve,
                                                     const float* __restrict__ lam,
                                                     const float* __restrict__ ctab,
                                                     const float* __restrict__ stab,
                                                     ushort* __restrict__ Qb,
                                                     ushort* __restrict__ Kb,
                                                     ushort* __restrict__ Vt) {
  const int K = DIMSZ;
  __shared__ __align__(16) ushort Ab[2][BM2 * BKS];  // 2 x 32KB
  __shared__ __align__(16) ushort Bb[2][BN2 * BKS];  // 2 x 32KB
  int tid = threadIdx.x;
  int wid = tid >> 6, lane = tid & 63;
  int lr = lane & 15, lg = lane >> 4;
  int m0 = blockIdx.x * BM2, n0 = blockIdx.y * BN2;
  int wm = (wid >> 2) * 128, wn = (wid & 3) * 64;
  int rs = lr & 7;

  // staging map (T2): thread -> (row = u*64 + tid>>3, slot = tid&7), slot holds chunk
  // (slot ^ row&7) -> pre-swizzled GLOBAL column, linear LDS (m173)
  int srow = tid >> 3;
  int sel = (((tid & 7) ^ (srow & 7)) << 3);
  const ushort* aSrc = A + (size_t)(m0 + srow) * K + sel;
  const ushort* bSrc = Bt + (size_t)(n0 + srow) * K + sel;
  int dstoff = tid * 8;

  f32x4 acc[8][4];
#pragma unroll
  for (int m = 0; m < 8; ++m)
#pragma unroll
    for (int n = 0; n < 4; ++n)
      acc[m][n] = (f32x4){0.f, 0.f, 0.f, 0.f};

  // prologue: tile 0 in canonical stream order
  GLOAD_LDS16(bSrc + 0 * 64 * K, &Bb[0][0 * 4096 + dstoff]);
  GLOAD_LDS16(bSrc + 1 * 64 * K, &Bb[0][1 * 4096 + dstoff]);
  GLOAD_LDS16(bSrc + 2 * 64 * K, &Bb[0][2 * 4096 + dstoff]);
  GLOAD_LDS16(bSrc + 3 * 64 * K, &Bb[0][3 * 4096 + dstoff]);
  GLOAD_LDS16(aSrc + 0 * 64 * K, &Ab[0][0 * 4096 + dstoff]);
  GLOAD_LDS16(aSrc + 2 * 64 * K, &Ab[0][2 * 4096 + dstoff]);
  GLOAD_LDS16(aSrc + 1 * 64 * K, &Ab[0][1 * 4096 + dstoff]);
  GLOAD_LDS16(aSrc + 3 * 64 * K, &Ab[0][3 * 4096 + dstoff]);

  bf16x8 bfr[4][2];

  for (int T = 0; T < 16; ++T) {
    const int cur = T & 1;
    const ushort* Ac = &Ab[cur][0];
    const ushort* Bc = &Bb[cur][0];
    ushort* An = &Ab[cur ^ 1][0];
    ushort* Bn = &Bb[cur ^ 1][0];
    const bool pre = (T + 1 < 16);
    const int k1 = (T + 1) * BKS;

    // -------- phase 0 --------
    asm volatile("s_waitcnt vmcnt(2)" ::: "memory");
    __builtin_amdgcn_s_barrier();
    asm volatile("" ::: "memory");
    if (pre) {
      GLOAD_LDS16(bSrc + (size_t)0 * 64 * K + k1, &Bn[0 * 4096 + dstoff]);
      GLOAD_LDS16(bSrc + (size_t)1 * 64 * K + k1, &Bn[1 * 4096 + dstoff]);
    }
#pragma unroll
    for (int n = 0; n < 4; ++n)
#pragma unroll
      for (int kk = 0; kk < 2; ++kk)
        bfr[n][kk] = *(const bf16x8*)&Bc[(wn + n * 16 + lr) * 64 + (((kk * 4 + lg) ^ rs) << 3)];
    QUAD(0);
    // -------- phase 1 --------
    __builtin_amdgcn_s_barrier();
    asm volatile("" ::: "memory");
    if (pre) {
      GLOAD_LDS16(bSrc + (size_t)2 * 64 * K + k1, &Bn[2 * 4096 + dstoff]);
      GLOAD_LDS16(bSrc + (size_t)3 * 64 * K + k1, &Bn[3 * 4096 + dstoff]);
    }
    QUAD(1);
    // -------- phase 2 --------
    if (pre) {
      asm volatile("s_waitcnt vmcnt(4)" ::: "memory");
    } else {
      asm volatile("s_waitcnt vmcnt(0)" ::: "memory");
    }
    __builtin_amdgcn_s_barrier();
    asm volatile("" ::: "memory");
    if (pre) {
      GLOAD_LDS16(aSrc + (size_t)0 * 64 * K + k1, &An[0 * 4096 + dstoff]);
      GLOAD_LDS16(aSrc + (size_t)2 * 64 * K + k1, &An[2 * 4096 + dstoff]);
    }
    QUAD(2);
    // -------- phase 3 --------
    __builtin_amdgcn_s_barrier();
    asm volatile("" ::: "memory");
    if (pre) {
      GLOAD_LDS16(aSrc + (size_t)1 * 64 * K + k1, &An[1 * 4096 + dstoff]);
      GLOAD_LDS16(aSrc + (size_t)3 * 64 * K + k1, &An[3 * 4096 + dstoff]);
    }
    QUAD(3);
  }
  __syncthreads();

  // ---- fused epilogue (token-ownership), two 64-token halves ----
  int sec = n0 >> 10;                   // 0=Q, 1=K, 2=V (block-uniform; 256 | 1024)
  int h = ((n0 & 1023) + wn) >> 6;      // head (wave-uniform)
  ushort* Tl = &Ab[0][0] + wid * 4096;  // 8KB slice per wave (all buffers dead)
  float l0 = lam[0], l1 = lam[1];

#pragma unroll
  for (int hf = 0; hf < 2; ++hf) {
    // write 4 m-fragments (64 tokens x 64 dims) bf16, dim-chunk XOR-swizzled
#pragma unroll
    for (int mi = 0; mi < 4; ++mi)
#pragma unroll
      for (int n = 0; n < 4; ++n)
#pragma unroll
        for (int r = 0; r < 4; ++r) {
          int tl = mi * 16 + lg * 4 + r;
          int d = n * 16 + lr;
          Tl[tl * 64 + ((((d >> 3) ^ (tl & 7)) << 3) | (d & 7))] = f2bf(acc[hf * 4 + mi][n][r]);
        }
    // each lane reads its own token row
    int tl = lane;
    float xv[64];
#pragma unroll
    for (int j = 0; j < 8; ++j) {
      u16x8 rw = *(const u16x8*)&Tl[tl * 64 + ((j ^ (tl & 7)) << 3)];
#pragma unroll
      for (int e = 0; e < 8; ++e) xv[j * 8 + e] = bf2f((ushort)rw[e]);
    }
    // RMSNorm in-lane
    float ss = 0.f;
#pragma unroll
    for (int i = 0; i < 64; ++i) ss += xv[i] * xv[i];
    float rinv = rsqrtf(ss * (1.0f / 64.0f) + 1e-6f);
#pragma unroll
    for (int i = 0; i < 64; ++i) xv[i] *= rinv;

    int row = m0 + wm + hf * 64 + tl;   // token id 0..4095
    int t = row & (T_SEQ - 1);
    int bb = row >> 11;
    int bh = bb * NH + h;

    if (sec < 2) {
      // RoPE in-lane: pairs (j, j+32)
      float cs[16], sn[16];
      const float4* cp = (const float4*)(ctab + t * 32);
      const float4* sp = (const float4*)(stab + t * 32);
#pragma unroll
      for (int j = 0; j < 4; ++j) {
        float4 c4 = cp[j], s4 = sp[j];
        cs[j * 4 + 0] = c4.x; cs[j * 4 + 1] = c4.y; cs[j * 4 + 2] = c4.z; cs[j * 4 + 3] = c4.w;
        sn[j * 4 + 0] = s4.x; sn[j * 4 + 1] = s4.y; sn[j * 4 + 2] = s4.z; sn[j * 4 + 3] = s4.w;
      }
#pragma unroll
      for (int j = 0; j < 16; ++j) {
        float a = xv[j], bv = xv[j + 32];
        xv[j] = a * cs[j] + bv * sn[j];
        xv[j + 32] = bv * cs[j] - a * sn[j];
      }
      float sc = (sec == 0) ? QSCALE : 1.0f;
      ushort* dst = (sec == 0 ? Qb : Kb) + ((size_t)bh * T_SEQ + t) * HDIM;
#pragma unroll
      for (int p = 0; p < 8; ++p) {
        uint4 wq = make_uint4(pk2(xv[8 * p] * sc, xv[8 * p + 1] * sc),
                              pk2(xv[8 * p + 2] * sc, xv[8 * p + 3] * sc),
                              pk2(xv[8 * p + 4] * sc, xv[8 * p + 5] * sc),
                              pk2(xv[8 * p + 6] * sc, xv[8 * p + 7] * sc));
        *((uint4*)dst + p) = wq;
      }
    } else {
      const float4* vp = (const float4*)(ve + ((size_t)(bb * T_SEQ + t)) * DIMSZ + h * HDIM);
#pragma unroll
      for (int j = 0; j < 16; ++j) {
        float4 vv4 = vp[j];
        xv[j * 4 + 0] = l0 * xv[j * 4 + 0] + l1 * vv4.x;
        xv[j * 4 + 1] = l0 * xv[j * 4 + 1] + l1 * vv4.y;
        xv[j * 4 + 2] = l0 * xv[j * 4 + 2] + l1 * vv4.z;
        xv[j * 4 + 3] = l0 * xv[j * 4 + 3] + l1 * vv4.w;
      }
      ushort* dst = Vt + (size_t)bh * HDIM * T_SEQ + t;
#pragma unroll
      for (int i = 0; i < 64; ++i)
        dst[(size_t)i * T_SEQ] = f2bf(xv[i]);
    }
  }
}

// ---------------- flash attention: LDS-shared K/V, dual-tile blocks (unchanged) ----
__global__ __launch_bounds__(512, 4) void attn_k(const ushort* __restrict__ Q,
                                                 const ushort* __restrict__ K,
                                                 const ushort* __restrict__ Vt,
                                                 ushort* __restrict__ Y) {
  int bh = blockIdx.x;    // 0..31 -> dispatch id % 8 = bh % 8 (XCD L2 locality)
  int pair = blockIdx.y;  // 0..15, heavy (pair=0 -> 32 tiles) first
  int tid = threadIdx.x;
  int wid = tid >> 6, lane = tid & 63;
  int lr = lane & 15, lg = lane >> 4;
  int b = bh >> 4, h = bh & 15;

  int NT = 32 - pair;                    // staged KV tiles: kb = 0..NT-1
  int grp = wid >> 2;                    // 0 -> tile pair, 1 -> tile 31-pair
  int myqb = grp ? (31 - pair) : pair;
  int mylast = grp ? (NT - 1) : pair;    // my diagonal (and last active) iter
  int strip = wid & 3;
  int r0 = myqb * 64 + strip * 16;

  __shared__ __align__(16) ushort Kl[2][KVB * HDIM];   // 2 x 8 KB
  __shared__ __align__(16) ushort Vl[2][KVB * HDIM];   // 2 x 8 KB ([d=64][key=64])
  __shared__ __align__(16) ushort Plds[8][16][72];

  const ushort* Kbh = K + (size_t)bh * T_SEQ * HDIM;
  const ushort* Vbh = Vt + (size_t)bh * HDIM * T_SEQ;

  // staging: thread t -> LDS (row = t>>3, 16B-chunk = t&7); source pre-swizzled
  int srow = tid >> 3, schunk = tid & 7;
  int sel = ((schunk ^ (srow & 7)) << 3);                 // element offset in 64-elem row
  const ushort* ksrc = Kbh + (size_t)srow * HDIM + sel;   // + kb*KVB*HDIM
  const ushort* vsrc = Vbh + (size_t)srow * T_SEQ + sel;  // + kb*KVB
  int ldst = wid << 9;                                    // wave-uniform LDS base (elems)

  // Q fragments (global, read once)
  const ushort* Qbase = Q + ((size_t)bh * T_SEQ + r0) * HDIM;
  bf16x8 aq[2];
#pragma unroll
  for (int kk = 0; kk < 2; ++kk)
    aq[kk] = *(const bf16x8*)(Qbase + (size_t)lr * HDIM + kk * 32 + lg * 8);

  // swizzled fragment column offsets (element units)
  int fcol[2];
  fcol[0] = ((0 + lg) ^ (lr & 7)) << 3;
  fcol[1] = ((4 + lg) ^ (lr & 7)) << 3;

  f32x4 o[4];
#pragma unroll
  for (int n = 0; n < 4; ++n) o[n] = (f32x4){0.f, 0.f, 0.f, 0.f};
  float lrow = 0.f;

  // prologue: stage tile 0 into buffer 0
  GLOAD_LDS16(ksrc, &Kl[0][ldst]);
  GLOAD_LDS16(vsrc, &Vl[0][ldst]);
  __syncthreads();

  int cur = 0;
  for (int kb = 0; kb < NT; ++kb) {
    // issue next tile's staging first (latency hides under compute)
    if (kb + 1 < NT) {
      GLOAD_LDS16(ksrc + (size_t)(kb + 1) * KVB * HDIM, &Kl[cur ^ 1][ldst]);
      GLOAD_LDS16(vsrc + (kb + 1) * KVB, &Vl[cur ^ 1][ldst]);
    }
    if (kb <= mylast) {
      const ushort* Kc = &Kl[cur][0];
      const ushort* Vc = &Vl[cur][0];
      // S^T = K . Q^T : lane holds S[q=r0+lr][key = kb*64 + n*16 + lg*4 + r]
      f32x4 s[4];
#pragma unroll
      for (int n = 0; n < 4; ++n) {
        f32x4 a = (f32x4){0.f, 0.f, 0.f, 0.f};
        bf16x8 kf0 = *(const bf16x8*)&Kc[(n * 16 + lr) * HDIM + fcol[0]];
        a = __builtin_amdgcn_mfma_f32_16x16x32_bf16(kf0, aq[0], a, 0, 0, 0);
        bf16x8 kf1 = *(const bf16x8*)&Kc[(n * 16 + lr) * HDIM + fcol[1]];
        a = __builtin_amdgcn_mfma_f32_16x16x32_bf16(kf1, aq[1], a, 0, 0, 0);
        s[n] = a;
      }
      // causal mask on my diagonal tile
      if (kb == mylast) {
        int qrow = r0 + lr;
        int kb0 = kb * KVB + lg * 4;
#pragma unroll
        for (int n = 0; n < 4; ++n)
#pragma unroll
          for (int r = 0; r < 4; ++r)
            if (kb0 + n * 16 + r > qrow) s[n][r] = -1e30f;
      }
      // P = exp2(S) (static shift: |arg| <= 11.08 after RMSNorm); lane-partial sum
      float psum = 0.f;
#pragma unroll
      for (int n = 0; n < 4; ++n) {
        float p0 = exp2f(s[n][0]), p1 = exp2f(s[n][1]);
        float p2 = exp2f(s[n][2]), p3 = exp2f(s[n][3]);
        psum += (p0 + p1) + (p2 + p3);
        uint2 w;
        w.x = pk2(p0, p1);
        w.y = pk2(p2, p3);
        *(uint2*)&Plds[wid][lr][n * 16 + lg * 4] = w;
      }
      lrow += psum;
      // PV: O^T += V^T . P^T
#pragma unroll
      for (int kk = 0; kk < 2; ++kk) {
        bf16x8 ap = *(const bf16x8*)&Plds[wid][lr][kk * 32 + lg * 8];
#pragma unroll
        for (int n = 0; n < 4; ++n) {
          bf16x8 vf = *(const bf16x8*)&Vc[(n * 16 + lr) * HDIM + fcol[kk]];
          o[n] = __builtin_amdgcn_mfma_f32_16x16x32_bf16(vf, ap, o[n], 0, 0, 0);
        }
      }
    }
    __syncthreads();  // staging landed (vmcnt 0) + buf[cur] consumed by all
    cur ^= 1;
  }
  // epilogue: complete row sum across lg groups, normalize, write
  lrow += __shfl_xor(lrow, 16);
  lrow += __shfl_xor(lrow, 32);
  float inv = 1.0f / lrow;
  int row = r0 + lr;
#pragma unroll
  for (int n = 0; n < 4; ++n) {
    uint2 w;
    w.x = pk2(o[n][0] * inv, o[n][1] * inv);
    w.y = pk2(o[n][2] * inv, o[n][3] * inv);
    *(uint2*)&Y[((size_t)b * T_SEQ + row) * DIMSZ + h * HDIM + n * 16 + lg * 4] = w;
  }
}

// ---------------- launch ----------------
extern "C" void kernel_launch(void* const* d_in, const int* in_sizes, int n_in,
                              void* d_out, int out_size, void* d_ws, size_t ws_size,
                              hipStream_t stream) {
  const float* x   = (const float*)d_in[0];
  const float* ve  = (const float*)d_in[1];
  const float* lam = (const float*)d_in[2];
  const float* w   = (const float*)d_in[4];  // (4, 1024, 1024)
  float* out = (float*)d_out;

  char* ws = (char*)d_ws;
  const size_t NTOK = (size_t)NBATCH * T_SEQ;          // 4096
  const size_t nX = NTOK * DIMSZ;                      // 4,194,304
  const size_t nW = 4ull * DIMSZ * DIMSZ;              // 4,194,304

  ushort* Xb   = (ushort*)(ws);                        // 8 MB  @ 0
  ushort* Wb   = (ushort*)(ws + 8388608);              // 8 MB  @ 8M
  ushort* Qb   = (ushort*)(ws + 16777216);             // 8 MB  @ 16M
  ushort* Kb   = (ushort*)(ws + 25165824);             // 8 MB  @ 24M
  ushort* Vt   = (ushort*)(ws + 33554432);             // 8 MB  @ 32M
  ushort* Yb   = (ushort*)(ws + 41943040);             // 8 MB  @ 40M
  float*  ctab = (float*)(ws + 50331648);              // 256 KB @ 48M
  float*  stab = (float*)(ws + 50593792);              // 256 KB

  conv_bf16_k<<<(int)(nX / 4 / 256), 256, 0, stream>>>(x, Xb, (int)nX);
  conv_bf16_k<<<(int)(nW / 4 / 256), 256, 0, stream>>>(w, Wb, (int)nW);
  rope_tab_k<<<(T_SEQ * 32) / 256, 256, 0, stream>>>(ctab, stab);

  // QKV GEMM (4096 x 3072 x 1024), 256^2 tiles, 8-phase pipeline, fused epilogue
  gemm_qkv_k<<<dim3(4096 / BM2, 3072 / BN2), 512, 0, stream>>>(Xb, Wb, ve, lam, ctab, stab,
                                                               Qb, Kb, Vt);

  attn_k<<<dim3(NBATCH * NH, 16), 512, 0, stream>>>(Qb, Kb, Vt, Yb);

  // out: (4096 x 1024) = Yb @ W3^T, f32 straight to d_out
  gemm_bt_k<float><<<dim3(4096 / BM, 1024 / BN), 256, 0, stream>>>(Yb, Wb + 3ull * DIMSZ * DIMSZ, out, 4096, 1024, 1024);
}

// Round 14
// 124.986 us; speedup vs baseline: 1.1719x; 1.1719x over previous
//
#include <hip/hip_runtime.h>
#include <hip/hip_bf16.h>
#include <stdint.h>

#define T_SEQ 2048
#define DIMSZ 1024
#define NH    16
#define HDIM  64
#define NBATCH 2
#define KVB   64
#define ATT_SCALE 0.12f
#define QSCALE (0.12f * 1.4426950408889634f)

typedef __attribute__((ext_vector_type(8))) __bf16 bf16x8;
typedef __attribute__((ext_vector_type(8))) ushort u16x8;
typedef __attribute__((ext_vector_type(4))) float f32x4;

#define GLOAD_LDS16(gp, lp)                                                            \
  __builtin_amdgcn_global_load_lds((const __attribute__((address_space(1))) void*)(gp),\
                                   (__attribute__((address_space(3))) void*)(lp),      \
                                   16, 0, 0)

__device__ __forceinline__ ushort f2bf(float f) {
  union { float f; uint32_t u; } v; v.f = f;
  uint32_t u = v.u;
  uint32_t r = (u + 0x7FFFu + ((u >> 16) & 1u)) >> 16;
  return (ushort)r;
}

__device__ __forceinline__ float bf2f(ushort h) {
  union { float f; uint32_t u; } v;
  v.u = ((uint32_t)h) << 16;
  return v.f;
}

// paired f32->bf16 (compiler fuses into v_cvt_pk_bf16_f32)
__device__ __forceinline__ uint32_t pk2(float a, float b) {
  union { __hip_bfloat162 h; uint32_t u; } cv;
  cv.h = __hip_bfloat162(__float2bfloat16(a), __float2bfloat16(b));
  return cv.u;
}

// ---------------- f32 -> bf16 convert (vectorized) ----------------
__global__ __launch_bounds__(256) void conv_bf16_k(const float* __restrict__ in,
                                                   ushort* __restrict__ out, int n) {
  int i = (blockIdx.x * 256 + threadIdx.x) * 4;
  if (i >= n) return;
  float4 v = *(const float4*)(in + i);
  ushort4 o;
  o.x = f2bf(v.x); o.y = f2bf(v.y); o.z = f2bf(v.z); o.w = f2bf(v.w);
  *(ushort4*)(out + i) = o;
}

// ---------------- RoPE tables: cos/sin (T x 32) ----------------
__global__ __launch_bounds__(256) void rope_tab_k(float* __restrict__ ctab,
                                                  float* __restrict__ stab) {
  int idx = blockIdx.x * 256 + threadIdx.x;  // t*32 + j
  if (idx >= T_SEQ * 32) return;
  int j = idx & 31, t = idx >> 5;
  float c = 1.f, s = 0.f;
  if (j < 16) {
    float inv = powf(1024.0f, -(float)j / 15.0f);  // (1/1024)^(j/15)
    float th = (float)t * inv;
    c = cosf(th);
    s = sinf(th);
  }
  ctab[idx] = c;
  stab[idx] = s;
}

#define BM 128
#define BN 128
#define BKS 64

// ---------------- out-projection GEMM: 64x128 tile, 2 blocks/CU ----------------
// M=4096, N=1024, K=1024. 128^2 would give grid=256 = exactly 1 block/CU: no
// co-residency, staging drains fully exposed. 64x128 -> grid (64,8)=512 blocks,
// 24KB LDS -> 2 blocks/CU; m114 implicit overlap covers the per-K-step drain.
// T2 swizzle: pre-swizzled global source, linear LDS, XOR'd fragment column.
__global__ __launch_bounds__(256) void gemm_out_k(const ushort* __restrict__ A,
                                                  const ushort* __restrict__ Bt,
                                                  float* __restrict__ C) {
  const int K = DIMSZ, N = DIMSZ;
  __shared__ __align__(16) ushort As[64 * BKS];   // 8 KB
  __shared__ __align__(16) ushort Bs[128 * BKS];  // 16 KB
  int tid = threadIdx.x;
  int wave = tid >> 6, lane = tid & 63;
  int lr = lane & 15, lg = lane >> 4;
  int m0 = blockIdx.x * 64, n0 = blockIdx.y * 128;
  int wm = (wave >> 1) * 32, wn = (wave & 1) * 64;

  int srow = tid >> 3;
  int sel = (((tid & 7) ^ (srow & 7)) << 3);  // pre-swizzled source column

  f32x4 acc[2][4];
#pragma unroll
  for (int m = 0; m < 2; ++m)
#pragma unroll
    for (int n = 0; n < 4; ++n)
      acc[m][n] = (f32x4){0.f, 0.f, 0.f, 0.f};

  for (int k0 = 0; k0 < K; k0 += BKS) {
#pragma unroll
    for (int it = 0; it < 2; ++it)
      GLOAD_LDS16(A + (size_t)(m0 + it * 32 + srow) * K + k0 + sel, &As[(it * 256 + tid) * 8]);
#pragma unroll
    for (int it = 0; it < 4; ++it)
      GLOAD_LDS16(Bt + (size_t)(n0 + it * 32 + srow) * K + k0 + sel, &Bs[(it * 256 + tid) * 8]);
    __syncthreads();
#pragma unroll
    for (int kk = 0; kk < 2; ++kk) {
      int cA = (((kk * 4 + lg) ^ (lr & 7)) << 3);
      bf16x8 af[2], bf[4];
#pragma unroll
      for (int m = 0; m < 2; ++m)
        af[m] = *(const bf16x8*)&As[(wm + m * 16 + lr) * BKS + cA];
#pragma unroll
      for (int n = 0; n < 4; ++n)
        bf[n] = *(const bf16x8*)&Bs[(wn + n * 16 + lr) * BKS + cA];
#pragma unroll
      for (int m = 0; m < 2; ++m)
#pragma unroll
        for (int n = 0; n < 4; ++n)
          acc[m][n] = __builtin_amdgcn_mfma_f32_16x16x32_bf16(af[m], bf[n], acc[m][n], 0, 0, 0);
    }
    __syncthreads();
  }
#pragma unroll
  for (int m = 0; m < 2; ++m)
#pragma unroll
    for (int n = 0; n < 4; ++n)
#pragma unroll
      for (int r = 0; r < 4; ++r) {
        int row = m0 + wm + m * 16 + lg * 4 + r;
        int col = n0 + wn + n * 16 + lr;
        C[(size_t)row * N + col] = acc[m][n][r];
      }
}

// ---------------- QKV GEMM: 128^2 single-buffer (R10 structure) + T2 swizzle ----------------
// R10 measured 80us with 9.5M LDS-conflict cycles at ~3 blocks/CU (LDS-pipe
// contended); the swizzle (verified 97x conflict removal in R11) is applied to
// the exact R10 kernel as the single change. Epilogue v2 token-ownership kept.
__global__ __launch_bounds__(256) void gemm_qkv_k(const ushort* __restrict__ A,
                                                  const ushort* __restrict__ Bt,
                                                  const float* __restrict__ ve,
                                                  const float* __restrict__ lam,
                                                  const float* __restrict__ ctab,
                                                  const float* __restrict__ stab,
                                                  ushort* __restrict__ Qb,
                                                  ushort* __restrict__ Kb,
                                                  ushort* __restrict__ Vt) {
  const int K = DIMSZ;
  __shared__ __align__(16) ushort As[BM * BKS];
  __shared__ __align__(16) ushort Bs[BN * BKS];
  int tid = threadIdx.x;
  int wave = tid >> 6, lane = tid & 63;
  int lr = lane & 15, lg = lane >> 4;
  int m0 = blockIdx.x * BM, n0 = blockIdx.y * BN;
  int wm = (wave >> 1) * 64, wn = (wave & 1) * 64;

  int srow = tid >> 3;
  int sel = (((tid & 7) ^ (srow & 7)) << 3);  // pre-swizzled source column

  f32x4 acc[4][4];
  for (int m = 0; m < 4; ++m)
    for (int n = 0; n < 4; ++n)
      acc[m][n] = (f32x4){0.f, 0.f, 0.f, 0.f};

  for (int k0 = 0; k0 < K; k0 += BKS) {
#pragma unroll
    for (int it = 0; it < 4; ++it) {
      GLOAD_LDS16(A + (size_t)(m0 + it * 32 + srow) * K + k0 + sel, &As[(it * 256 + tid) * 8]);
      GLOAD_LDS16(Bt + (size_t)(n0 + it * 32 + srow) * K + k0 + sel, &Bs[(it * 256 + tid) * 8]);
    }
    __syncthreads();
#pragma unroll
    for (int kk = 0; kk < 2; ++kk) {
      int cA = (((kk * 4 + lg) ^ (lr & 7)) << 3);
      bf16x8 af[4], bf[4];
#pragma unroll
      for (int m = 0; m < 4; ++m)
        af[m] = *(const bf16x8*)&As[(wm + m * 16 + lr) * BKS + cA];
#pragma unroll
      for (int n = 0; n < 4; ++n)
        bf[n] = *(const bf16x8*)&Bs[(wn + n * 16 + lr) * BKS + cA];
#pragma unroll
      for (int m = 0; m < 4; ++m)
#pragma unroll
        for (int n = 0; n < 4; ++n)
          acc[m][n] = __builtin_amdgcn_mfma_f32_16x16x32_bf16(af[m], bf[n], acc[m][n], 0, 0, 0);
    }
    __syncthreads();
  }

  // ---- epilogue v2: per-wave LDS transpose to token-ownership (R10, unchanged) ----
  int sec = n0 >> 10;                   // 0=Q, 1=K, 2=V (block-uniform)
  int h = ((n0 & 1023) + wn) >> 6;      // head (wave-uniform)
  ushort* Tl = (wave < 2 ? As : Bs) + (wave & 1) * 4096;

#pragma unroll
  for (int m = 0; m < 4; ++m)
#pragma unroll
    for (int n = 0; n < 4; ++n)
#pragma unroll
      for (int r = 0; r < 4; ++r) {
        int tl = m * 16 + lg * 4 + r;
        int d = n * 16 + lr;
        Tl[tl * 64 + ((((d >> 3) ^ (tl & 7)) << 3) | (d & 7))] = f2bf(acc[m][n][r]);
      }

  int tl = lane;
  float xv[64];
#pragma unroll
  for (int j = 0; j < 8; ++j) {
    u16x8 rw = *(const u16x8*)&Tl[tl * 64 + ((j ^ (tl & 7)) << 3)];
#pragma unroll
    for (int e = 0; e < 8; ++e) xv[j * 8 + e] = bf2f((ushort)rw[e]);
  }

  float ss = 0.f;
#pragma unroll
  for (int i = 0; i < 64; ++i) ss += xv[i] * xv[i];
  float rinv = rsqrtf(ss * (1.0f / 64.0f) + 1e-6f);
#pragma unroll
  for (int i = 0; i < 64; ++i) xv[i] *= rinv;

  int row = m0 + wm + tl;               // token id 0..4095
  int t = row & (T_SEQ - 1);
  int bb = row >> 11;
  int bh = bb * NH + h;

  if (sec < 2) {
    float cs[16], sn[16];
    const float4* cp = (const float4*)(ctab + t * 32);
    const float4* sp = (const float4*)(stab + t * 32);
#pragma unroll
    for (int j = 0; j < 4; ++j) {
      float4 c4 = cp[j], s4 = sp[j];
      cs[j * 4 + 0] = c4.x; cs[j * 4 + 1] = c4.y; cs[j * 4 + 2] = c4.z; cs[j * 4 + 3] = c4.w;
      sn[j * 4 + 0] = s4.x; sn[j * 4 + 1] = s4.y; sn[j * 4 + 2] = s4.z; sn[j * 4 + 3] = s4.w;
    }
#pragma unroll
    for (int j = 0; j < 16; ++j) {
      float a = xv[j], bv = xv[j + 32];
      xv[j] = a * cs[j] + bv * sn[j];
      xv[j + 32] = bv * cs[j] - a * sn[j];
    }
    float sc = (sec == 0) ? QSCALE : 1.0f;
    ushort* dst = (sec == 0 ? Qb : Kb) + ((size_t)bh * T_SEQ + t) * HDIM;
#pragma unroll
    for (int p = 0; p < 8; ++p) {
      uint4 wq = make_uint4(pk2(xv[8 * p] * sc, xv[8 * p + 1] * sc),
                            pk2(xv[8 * p + 2] * sc, xv[8 * p + 3] * sc),
                            pk2(xv[8 * p + 4] * sc, xv[8 * p + 5] * sc),
                            pk2(xv[8 * p + 6] * sc, xv[8 * p + 7] * sc));
      *((uint4*)dst + p) = wq;
    }
  } else {
    float l0 = lam[0], l1 = lam[1];
    const float4* vp = (const float4*)(ve + ((size_t)(bb * T_SEQ + t)) * DIMSZ + h * HDIM);
#pragma unroll
    for (int j = 0; j < 16; ++j) {
      float4 vv4 = vp[j];
      xv[j * 4 + 0] = l0 * xv[j * 4 + 0] + l1 * vv4.x;
      xv[j * 4 + 1] = l0 * xv[j * 4 + 1] + l1 * vv4.y;
      xv[j * 4 + 2] = l0 * xv[j * 4 + 2] + l1 * vv4.z;
      xv[j * 4 + 3] = l0 * xv[j * 4 + 3] + l1 * vv4.w;
    }
    ushort* dst = Vt + (size_t)bh * HDIM * T_SEQ + t;
#pragma unroll
    for (int i = 0; i < 64; ++i)
      dst[(size_t)i * T_SEQ] = f2bf(xv[i]);
  }
}

// ---------------- flash attention: LDS-shared K/V, dual-tile blocks (unchanged) ----
__global__ __launch_bounds__(512, 4) void attn_k(const ushort* __restrict__ Q,
                                                 const ushort* __restrict__ K,
                                                 const ushort* __restrict__ Vt,
                                                 ushort* __restrict__ Y) {
  int bh = blockIdx.x;    // 0..31 -> dispatch id % 8 = bh % 8 (XCD L2 locality)
  int pair = blockIdx.y;  // 0..15, heavy (pair=0 -> 32 tiles) first
  int tid = threadIdx.x;
  int wid = tid >> 6, lane = tid & 63;
  int lr = lane & 15, lg = lane >> 4;
  int b = bh >> 4, h = bh & 15;

  int NT = 32 - pair;                    // staged KV tiles: kb = 0..NT-1
  int grp = wid >> 2;                    // 0 -> tile pair, 1 -> tile 31-pair
  int myqb = grp ? (31 - pair) : pair;
  int mylast = grp ? (NT - 1) : pair;    // my diagonal (and last active) iter
  int strip = wid & 3;
  int r0 = myqb * 64 + strip * 16;

  __shared__ __align__(16) ushort Kl[2][KVB * HDIM];   // 2 x 8 KB
  __shared__ __align__(16) ushort Vl[2][KVB * HDIM];   // 2 x 8 KB ([d=64][key=64])
  __shared__ __align__(16) ushort Plds[8][16][72];

  const ushort* Kbh = K + (size_t)bh * T_SEQ * HDIM;
  const ushort* Vbh = Vt + (size_t)bh * HDIM * T_SEQ;

  // staging: thread t -> LDS (row = t>>3, 16B-chunk = t&7); source pre-swizzled
  int srow = tid >> 3, schunk = tid & 7;
  int sel = ((schunk ^ (srow & 7)) << 3);                 // element offset in 64-elem row
  const ushort* ksrc = Kbh + (size_t)srow * HDIM + sel;   // + kb*KVB*HDIM
  const ushort* vsrc = Vbh + (size_t)srow * T_SEQ + sel;  // + kb*KVB
  int ldst = wid << 9;                                    // wave-uniform LDS base (elems)

  // Q fragments (global, read once)
  const ushort* Qbase = Q + ((size_t)bh * T_SEQ + r0) * HDIM;
  bf16x8 aq[2];
#pragma unroll
  for (int kk = 0; kk < 2; ++kk)
    aq[kk] = *(const bf16x8*)(Qbase + (size_t)lr * HDIM + kk * 32 + lg * 8);

  // swizzled fragment column offsets (element units)
  int fcol[2];
  fcol[0] = ((0 + lg) ^ (lr & 7)) << 3;
  fcol[1] = ((4 + lg) ^ (lr & 7)) << 3;

  f32x4 o[4];
#pragma unroll
  for (int n = 0; n < 4; ++n) o[n] = (f32x4){0.f, 0.f, 0.f, 0.f};
  float lrow = 0.f;

  // prologue: stage tile 0 into buffer 0
  GLOAD_LDS16(ksrc, &Kl[0][ldst]);
  GLOAD_LDS16(vsrc, &Vl[0][ldst]);
  __syncthreads();

  int cur = 0;
  for (int kb = 0; kb < NT; ++kb) {
    // issue next tile's staging first (latency hides under compute)
    if (kb + 1 < NT) {
      GLOAD_LDS16(ksrc + (size_t)(kb + 1) * KVB * HDIM, &Kl[cur ^ 1][ldst]);
      GLOAD_LDS16(vsrc + (kb + 1) * KVB, &Vl[cur ^ 1][ldst]);
    }
    if (kb <= mylast) {
      const ushort* Kc = &Kl[cur][0];
      const ushort* Vc = &Vl[cur][0];
      // S^T = K . Q^T : lane holds S[q=r0+lr][key = kb*64 + n*16 + lg*4 + r]
      f32x4 s[4];
#pragma unroll
      for (int n = 0; n < 4; ++n) {
        f32x4 a = (f32x4){0.f, 0.f, 0.f, 0.f};
        bf16x8 kf0 = *(const bf16x8*)&Kc[(n * 16 + lr) * HDIM + fcol[0]];
        a = __builtin_amdgcn_mfma_f32_16x16x32_bf16(kf0, aq[0], a, 0, 0, 0);
        bf16x8 kf1 = *(const bf16x8*)&Kc[(n * 16 + lr) * HDIM + fcol[1]];
        a = __builtin_amdgcn_mfma_f32_16x16x32_bf16(kf1, aq[1], a, 0, 0, 0);
        s[n] = a;
      }
      // causal mask on my diagonal tile
      if (kb == mylast) {
        int qrow = r0 + lr;
        int kb0 = kb * KVB + lg * 4;
#pragma unroll
        for (int n = 0; n < 4; ++n)
#pragma unroll
          for (int r = 0; r < 4; ++r)
            if (kb0 + n * 16 + r > qrow) s[n][r] = -1e30f;
      }
      // P = exp2(S) (static shift: |arg| <= 11.08 after RMSNorm); lane-partial sum
      float psum = 0.f;
#pragma unroll
      for (int n = 0; n < 4; ++n) {
        float p0 = exp2f(s[n][0]), p1 = exp2f(s[n][1]);
        float p2 = exp2f(s[n][2]), p3 = exp2f(s[n][3]);
        psum += (p0 + p1) + (p2 + p3);
        uint2 w;
        w.x = pk2(p0, p1);
        w.y = pk2(p2, p3);
        *(uint2*)&Plds[wid][lr][n * 16 + lg * 4] = w;
      }
      lrow += psum;
      // PV: O^T += V^T . P^T
#pragma unroll
      for (int kk = 0; kk < 2; ++kk) {
        bf16x8 ap = *(const bf16x8*)&Plds[wid][lr][kk * 32 + lg * 8];
#pragma unroll
        for (int n = 0; n < 4; ++n) {
          bf16x8 vf = *(const bf16x8*)&Vc[(n * 16 + lr) * HDIM + fcol[kk]];
          o[n] = __builtin_amdgcn_mfma_f32_16x16x32_bf16(vf, ap, o[n], 0, 0, 0);
        }
      }
    }
    __syncthreads();  // staging landed (vmcnt 0) + buf[cur] consumed by all
    cur ^= 1;
  }
  // epilogue: complete row sum across lg groups, normalize, write
  lrow += __shfl_xor(lrow, 16);
  lrow += __shfl_xor(lrow, 32);
  float inv = 1.0f / lrow;
  int row = r0 + lr;
#pragma unroll
  for (int n = 0; n < 4; ++n) {
    uint2 w;
    w.x = pk2(o[n][0] * inv, o[n][1] * inv);
    w.y = pk2(o[n][2] * inv, o[n][3] * inv);
    *(uint2*)&Y[((size_t)b * T_SEQ + row) * DIMSZ + h * HDIM + n * 16 + lg * 4] = w;
  }
}

// ---------------- launch ----------------
extern "C" void kernel_launch(void* const* d_in, const int* in_sizes, int n_in,
                              void* d_out, int out_size, void* d_ws, size_t ws_size,
                              hipStream_t stream) {
  const float* x   = (const float*)d_in[0];
  const float* ve  = (const float*)d_in[1];
  const float* lam = (const float*)d_in[2];
  const float* w   = (const float*)d_in[4];  // (4, 1024, 1024)
  float* out = (float*)d_out;

  char* ws = (char*)d_ws;
  const size_t NTOK = (size_t)NBATCH * T_SEQ;          // 4096
  const size_t nX = NTOK * DIMSZ;                      // 4,194,304
  const size_t nW = 4ull * DIMSZ * DIMSZ;              // 4,194,304

  ushort* Xb   = (ushort*)(ws);                        // 8 MB  @ 0
  ushort* Wb   = (ushort*)(ws + 8388608);              // 8 MB  @ 8M
  ushort* Qb   = (ushort*)(ws + 16777216);             // 8 MB  @ 16M
  ushort* Kb   = (ushort*)(ws + 25165824);             // 8 MB  @ 24M
  ushort* Vt   = (ushort*)(ws + 33554432);             // 8 MB  @ 32M
  ushort* Yb   = (ushort*)(ws + 41943040);             // 8 MB  @ 40M
  float*  ctab = (float*)(ws + 50331648);              // 256 KB @ 48M
  float*  stab = (float*)(ws + 50593792);              // 256 KB

  conv_bf16_k<<<(int)(nX / 4 / 256), 256, 0, stream>>>(x, Xb, (int)nX);
  conv_bf16_k<<<(int)(nW / 4 / 256), 256, 0, stream>>>(w, Wb, (int)nW);
  rope_tab_k<<<(T_SEQ * 32) / 256, 256, 0, stream>>>(ctab, stab);

  // QKV GEMM (4096 x 3072 x 1024), 128^2 single-buffer + swizzle, fused epilogue
  gemm_qkv_k<<<dim3(4096 / BM, 3072 / BN), 256, 0, stream>>>(Xb, Wb, ve, lam, ctab, stab,
                                                             Qb, Kb, Vt);

  attn_k<<<dim3(NBATCH * NH, 16), 512, 0, stream>>>(Qb, Kb, Vt, Yb);

  // out-proj: (4096 x 1024) = Yb @ W3^T, 64x128 tiles (512 blocks, 2/CU)
  gemm_out_k<<<dim3(4096 / 64, 1024 / 128), 256, 0, stream>>>(Yb, Wb + 3ull * DIMSZ * DIMSZ, out);
}

// Round 15
// 120.898 us; speedup vs baseline: 1.2116x; 1.0338x over previous
//
#include <hip/hip_runtime.h>
#include <hip/hip_bf16.h>
#include <stdint.h>

#define T_SEQ 2048
#define DIMSZ 1024
#define NH    16
#define HDIM  64
#define NBATCH 2
#define KVB   64
#define ATT_SCALE 0.12f
#define QSCALE (0.12f * 1.4426950408889634f)

typedef __attribute__((ext_vector_type(8))) __bf16 bf16x8;
typedef __attribute__((ext_vector_type(8))) ushort u16x8;
typedef __attribute__((ext_vector_type(4))) float f32x4;

#define GLOAD_LDS16(gp, lp)                                                            \
  __builtin_amdgcn_global_load_lds((const __attribute__((address_space(1))) void*)(gp),\
                                   (__attribute__((address_space(3))) void*)(lp),      \
                                   16, 0, 0)

__device__ __forceinline__ ushort f2bf(float f) {
  union { float f; uint32_t u; } v; v.f = f;
  uint32_t u = v.u;
  uint32_t r = (u + 0x7FFFu + ((u >> 16) & 1u)) >> 16;
  return (ushort)r;
}

__device__ __forceinline__ float bf2f(ushort h) {
  union { float f; uint32_t u; } v;
  v.u = ((uint32_t)h) << 16;
  return v.f;
}

// paired f32->bf16 (compiler fuses into v_cvt_pk_bf16_f32)
__device__ __forceinline__ uint32_t pk2(float a, float b) {
  union { __hip_bfloat162 h; uint32_t u; } cv;
  cv.h = __hip_bfloat162(__float2bfloat16(a), __float2bfloat16(b));
  return cv.u;
}

// ---------------- f32 -> bf16 convert (vectorized) ----------------
__global__ __launch_bounds__(256) void conv_bf16_k(const float* __restrict__ in,
                                                   ushort* __restrict__ out, int n) {
  int i = (blockIdx.x * 256 + threadIdx.x) * 4;
  if (i >= n) return;
  float4 v = *(const float4*)(in + i);
  ushort4 o;
  o.x = f2bf(v.x); o.y = f2bf(v.y); o.z = f2bf(v.z); o.w = f2bf(v.w);
  *(ushort4*)(out + i) = o;
}

// ---------------- RoPE tables: cos/sin (T x 32) ----------------
__global__ __launch_bounds__(256) void rope_tab_k(float* __restrict__ ctab,
                                                  float* __restrict__ stab) {
  int idx = blockIdx.x * 256 + threadIdx.x;  // t*32 + j
  if (idx >= T_SEQ * 32) return;
  int j = idx & 31, t = idx >> 5;
  float c = 1.f, s = 0.f;
  if (j < 16) {
    float inv = powf(1024.0f, -(float)j / 15.0f);  // (1/1024)^(j/15)
    float th = (float)t * inv;
    c = cosf(th);
    s = sinf(th);
  }
  ctab[idx] = c;
  stab[idx] = s;
}

#define BM 128
#define BN 128
#define BKS 64

// ---------------- out-projection GEMM: 64x128 tile, 2 blocks/CU ----------------
__global__ __launch_bounds__(256) void gemm_out_k(const ushort* __restrict__ A,
                                                  const ushort* __restrict__ Bt,
                                                  float* __restrict__ C) {
  const int K = DIMSZ, N = DIMSZ;
  __shared__ __align__(16) ushort As[64 * BKS];   // 8 KB
  __shared__ __align__(16) ushort Bs[128 * BKS];  // 16 KB
  int tid = threadIdx.x;
  int wave = tid >> 6, lane = tid & 63;
  int lr = lane & 15, lg = lane >> 4;
  int m0 = blockIdx.x * 64, n0 = blockIdx.y * 128;
  int wm = (wave >> 1) * 32, wn = (wave & 1) * 64;

  int srow = tid >> 3;
  int sel = (((tid & 7) ^ (srow & 7)) << 3);  // pre-swizzled source column

  f32x4 acc[2][4];
#pragma unroll
  for (int m = 0; m < 2; ++m)
#pragma unroll
    for (int n = 0; n < 4; ++n)
      acc[m][n] = (f32x4){0.f, 0.f, 0.f, 0.f};

  for (int k0 = 0; k0 < K; k0 += BKS) {
#pragma unroll
    for (int it = 0; it < 2; ++it)
      GLOAD_LDS16(A + (size_t)(m0 + it * 32 + srow) * K + k0 + sel, &As[(it * 256 + tid) * 8]);
#pragma unroll
    for (int it = 0; it < 4; ++it)
      GLOAD_LDS16(Bt + (size_t)(n0 + it * 32 + srow) * K + k0 + sel, &Bs[(it * 256 + tid) * 8]);
    __syncthreads();
#pragma unroll
    for (int kk = 0; kk < 2; ++kk) {
      int cA = (((kk * 4 + lg) ^ (lr & 7)) << 3);
      bf16x8 af[2], bf[4];
#pragma unroll
      for (int m = 0; m < 2; ++m)
        af[m] = *(const bf16x8*)&As[(wm + m * 16 + lr) * BKS + cA];
#pragma unroll
      for (int n = 0; n < 4; ++n)
        bf[n] = *(const bf16x8*)&Bs[(wn + n * 16 + lr) * BKS + cA];
#pragma unroll
      for (int m = 0; m < 2; ++m)
#pragma unroll
        for (int n = 0; n < 4; ++n)
          acc[m][n] = __builtin_amdgcn_mfma_f32_16x16x32_bf16(af[m], bf[n], acc[m][n], 0, 0, 0);
    }
    __syncthreads();
  }
#pragma unroll
  for (int m = 0; m < 2; ++m)
#pragma unroll
    for (int n = 0; n < 4; ++n)
#pragma unroll
      for (int r = 0; r < 4; ++r) {
        int row = m0 + wm + m * 16 + lg * 4 + r;
        int col = n0 + wn + n * 16 + lr;
        C[(size_t)row * N + col] = acc[m][n][r];
      }
}

// ---------------- QKV GEMM: 128^2 single-buffer + T2 swizzle (R14, unchanged) ----------------
__global__ __launch_bounds__(256) void gemm_qkv_k(const ushort* __restrict__ A,
                                                  const ushort* __restrict__ Bt,
                                                  const float* __restrict__ ve,
                                                  const float* __restrict__ lam,
                                                  const float* __restrict__ ctab,
                                                  const float* __restrict__ stab,
                                                  ushort* __restrict__ Qb,
                                                  ushort* __restrict__ Kb,
                                                  ushort* __restrict__ Vt) {
  const int K = DIMSZ;
  __shared__ __align__(16) ushort As[BM * BKS];
  __shared__ __align__(16) ushort Bs[BN * BKS];
  int tid = threadIdx.x;
  int wave = tid >> 6, lane = tid & 63;
  int lr = lane & 15, lg = lane >> 4;
  int m0 = blockIdx.x * BM, n0 = blockIdx.y * BN;
  int wm = (wave >> 1) * 64, wn = (wave & 1) * 64;

  int srow = tid >> 3;
  int sel = (((tid & 7) ^ (srow & 7)) << 3);  // pre-swizzled source column

  f32x4 acc[4][4];
  for (int m = 0; m < 4; ++m)
    for (int n = 0; n < 4; ++n)
      acc[m][n] = (f32x4){0.f, 0.f, 0.f, 0.f};

  for (int k0 = 0; k0 < K; k0 += BKS) {
#pragma unroll
    for (int it = 0; it < 4; ++it) {
      GLOAD_LDS16(A + (size_t)(m0 + it * 32 + srow) * K + k0 + sel, &As[(it * 256 + tid) * 8]);
      GLOAD_LDS16(Bt + (size_t)(n0 + it * 32 + srow) * K + k0 + sel, &Bs[(it * 256 + tid) * 8]);
    }
    __syncthreads();
#pragma unroll
    for (int kk = 0; kk < 2; ++kk) {
      int cA = (((kk * 4 + lg) ^ (lr & 7)) << 3);
      bf16x8 af[4], bf[4];
#pragma unroll
      for (int m = 0; m < 4; ++m)
        af[m] = *(const bf16x8*)&As[(wm + m * 16 + lr) * BKS + cA];
#pragma unroll
      for (int n = 0; n < 4; ++n)
        bf[n] = *(const bf16x8*)&Bs[(wn + n * 16 + lr) * BKS + cA];
#pragma unroll
      for (int m = 0; m < 4; ++m)
#pragma unroll
        for (int n = 0; n < 4; ++n)
          acc[m][n] = __builtin_amdgcn_mfma_f32_16x16x32_bf16(af[m], bf[n], acc[m][n], 0, 0, 0);
    }
    __syncthreads();
  }

  // ---- epilogue v2: per-wave LDS transpose to token-ownership ----
  int sec = n0 >> 10;                   // 0=Q, 1=K, 2=V (block-uniform)
  int h = ((n0 & 1023) + wn) >> 6;      // head (wave-uniform)
  ushort* Tl = (wave < 2 ? As : Bs) + (wave & 1) * 4096;

#pragma unroll
  for (int m = 0; m < 4; ++m)
#pragma unroll
    for (int n = 0; n < 4; ++n)
#pragma unroll
      for (int r = 0; r < 4; ++r) {
        int tl = m * 16 + lg * 4 + r;
        int d = n * 16 + lr;
        Tl[tl * 64 + ((((d >> 3) ^ (tl & 7)) << 3) | (d & 7))] = f2bf(acc[m][n][r]);
      }

  int tl = lane;
  float xv[64];
#pragma unroll
  for (int j = 0; j < 8; ++j) {
    u16x8 rw = *(const u16x8*)&Tl[tl * 64 + ((j ^ (tl & 7)) << 3)];
#pragma unroll
    for (int e = 0; e < 8; ++e) xv[j * 8 + e] = bf2f((ushort)rw[e]);
  }

  float ss = 0.f;
#pragma unroll
  for (int i = 0; i < 64; ++i) ss += xv[i] * xv[i];
  float rinv = rsqrtf(ss * (1.0f / 64.0f) + 1e-6f);
#pragma unroll
  for (int i = 0; i < 64; ++i) xv[i] *= rinv;

  int row = m0 + wm + tl;               // token id 0..4095
  int t = row & (T_SEQ - 1);
  int bb = row >> 11;
  int bh = bb * NH + h;

  if (sec < 2) {
    float cs[16], sn[16];
    const float4* cp = (const float4*)(ctab + t * 32);
    const float4* sp = (const float4*)(stab + t * 32);
#pragma unroll
    for (int j = 0; j < 4; ++j) {
      float4 c4 = cp[j], s4 = sp[j];
      cs[j * 4 + 0] = c4.x; cs[j * 4 + 1] = c4.y; cs[j * 4 + 2] = c4.z; cs[j * 4 + 3] = c4.w;
      sn[j * 4 + 0] = s4.x; sn[j * 4 + 1] = s4.y; sn[j * 4 + 2] = s4.z; sn[j * 4 + 3] = s4.w;
    }
#pragma unroll
    for (int j = 0; j < 16; ++j) {
      float a = xv[j], bv = xv[j + 32];
      xv[j] = a * cs[j] + bv * sn[j];
      xv[j + 32] = bv * cs[j] - a * sn[j];
    }
    float sc = (sec == 0) ? QSCALE : 1.0f;
    ushort* dst = (sec == 0 ? Qb : Kb) + ((size_t)bh * T_SEQ + t) * HDIM;
#pragma unroll
    for (int p = 0; p < 8; ++p) {
      uint4 wq = make_uint4(pk2(xv[8 * p] * sc, xv[8 * p + 1] * sc),
                            pk2(xv[8 * p + 2] * sc, xv[8 * p + 3] * sc),
                            pk2(xv[8 * p + 4] * sc, xv[8 * p + 5] * sc),
                            pk2(xv[8 * p + 6] * sc, xv[8 * p + 7] * sc));
      *((uint4*)dst + p) = wq;
    }
  } else {
    float l0 = lam[0], l1 = lam[1];
    const float4* vp = (const float4*)(ve + ((size_t)(bb * T_SEQ + t)) * DIMSZ + h * HDIM);
#pragma unroll
    for (int j = 0; j < 16; ++j) {
      float4 vv4 = vp[j];
      xv[j * 4 + 0] = l0 * xv[j * 4 + 0] + l1 * vv4.x;
      xv[j * 4 + 1] = l0 * xv[j * 4 + 1] + l1 * vv4.y;
      xv[j * 4 + 2] = l0 * xv[j * 4 + 2] + l1 * vv4.z;
      xv[j * 4 + 3] = l0 * xv[j * 4 + 3] + l1 * vv4.w;
    }
    ushort* dst = Vt + (size_t)bh * HDIM * T_SEQ + t;
#pragma unroll
    for (int i = 0; i < 64; ++i)
      dst[(size_t)i * T_SEQ] = f2bf(xv[i]);
  }
}

// ---------------- flash attention v3: one q-tile per 4-wave block, zero idle waves ----
// R8's dual-tile block wasted ~32% of wave-slots (group-0 idle for kb > pair) and
// capped residency at 8 waves/CU. Now: grid (bh=32, y=32), 256 thr / 4 waves, one
// 64-row q-tile (qb = 31-y, heavy first for LPT); EVERY wave runs exactly qb+1 KV
// iterations (no idle guard). LDS 41KB -> 3 blocks/CU = 12 waves/CU resident.
// K/V staged once per block per tile into dbuf LDS (2 gload/arr, swizzled source).
__global__ __launch_bounds__(256, 3) void attn_k(const ushort* __restrict__ Q,
                                                 const ushort* __restrict__ K,
                                                 const ushort* __restrict__ Vt,
                                                 ushort* __restrict__ Y) {
  int bh = blockIdx.x;    // 0..31 -> dispatch id % 8 = bh % 8 (XCD L2 locality)
  int qb = 31 - blockIdx.y;  // heavy blocks dispatch first
  int tid = threadIdx.x;
  int wid = tid >> 6, lane = tid & 63;
  int lr = lane & 15, lg = lane >> 4;
  int b = bh >> 4, h = bh & 15;

  int r0 = qb * 64 + wid * 16;
  int nkv = qb + 1;

  __shared__ __align__(16) ushort Kl[2][KVB * HDIM];   // 2 x 8 KB
  __shared__ __align__(16) ushort Vl[2][KVB * HDIM];   // 2 x 8 KB ([d=64][key=64])
  __shared__ __align__(16) ushort Plds[4][16][72];

  const ushort* Kbh = K + (size_t)bh * T_SEQ * HDIM;
  const ushort* Vbh = Vt + (size_t)bh * HDIM * T_SEQ;

  // staging: 2 insts per array; inst i: thread t -> LDS elem t*8 + i*2048
  // (row = (t>>3)+32i, slot = t&7); source pre-swizzled chunk = slot ^ (row&7)
  int sr = tid >> 3;
  int sel = (((tid & 7) ^ (sr & 7)) << 3);
  const ushort* ksrc0 = Kbh + (size_t)sr * HDIM + sel;
  const ushort* ksrc1 = Kbh + (size_t)(sr + 32) * HDIM + sel;
  const ushort* vsrc0 = Vbh + (size_t)sr * T_SEQ + sel;
  const ushort* vsrc1 = Vbh + (size_t)(sr + 32) * T_SEQ + sel;
  int ld0 = tid * 8, ld1 = tid * 8 + 2048;  // element offsets

  // Q fragments (global, read once)
  const ushort* Qbase = Q + ((size_t)bh * T_SEQ + r0) * HDIM;
  bf16x8 aq[2];
#pragma unroll
  for (int kk = 0; kk < 2; ++kk)
    aq[kk] = *(const bf16x8*)(Qbase + (size_t)lr * HDIM + kk * 32 + lg * 8);

  // swizzled fragment column offsets (element units)
  int fcol[2];
  fcol[0] = ((0 + lg) ^ (lr & 7)) << 3;
  fcol[1] = ((4 + lg) ^ (lr & 7)) << 3;

  f32x4 o[4];
#pragma unroll
  for (int n = 0; n < 4; ++n) o[n] = (f32x4){0.f, 0.f, 0.f, 0.f};
  float lrow = 0.f;

  // prologue: stage tile 0 into buffer 0
  GLOAD_LDS16(ksrc0, &Kl[0][ld0]);
  GLOAD_LDS16(ksrc1, &Kl[0][ld1]);
  GLOAD_LDS16(vsrc0, &Vl[0][ld0]);
  GLOAD_LDS16(vsrc1, &Vl[0][ld1]);
  __syncthreads();

  for (int kb = 0; kb < nkv; ++kb) {
    int cur = kb & 1;
    // issue next tile's staging first (latency hides under compute)
    if (kb + 1 < nkv) {
      size_t ko = (size_t)(kb + 1) * KVB * HDIM;
      int vo = (kb + 1) * KVB;
      GLOAD_LDS16(ksrc0 + ko, &Kl[cur ^ 1][ld0]);
      GLOAD_LDS16(ksrc1 + ko, &Kl[cur ^ 1][ld1]);
      GLOAD_LDS16(vsrc0 + vo, &Vl[cur ^ 1][ld0]);
      GLOAD_LDS16(vsrc1 + vo, &Vl[cur ^ 1][ld1]);
    }
    const ushort* Kc = &Kl[cur][0];
    const ushort* Vc = &Vl[cur][0];
    // S^T = K . Q^T : lane holds S[q=r0+lr][key = kb*64 + n*16 + lg*4 + r]
    f32x4 s[4];
#pragma unroll
    for (int n = 0; n < 4; ++n) {
      f32x4 a = (f32x4){0.f, 0.f, 0.f, 0.f};
      bf16x8 kf0 = *(const bf16x8*)&Kc[(n * 16 + lr) * HDIM + fcol[0]];
      a = __builtin_amdgcn_mfma_f32_16x16x32_bf16(kf0, aq[0], a, 0, 0, 0);
      bf16x8 kf1 = *(const bf16x8*)&Kc[(n * 16 + lr) * HDIM + fcol[1]];
      a = __builtin_amdgcn_mfma_f32_16x16x32_bf16(kf1, aq[1], a, 0, 0, 0);
      s[n] = a;
    }
    // causal mask on the diagonal tile
    if (kb == nkv - 1) {
      int qrow = r0 + lr;
      int kb0 = kb * KVB + lg * 4;
#pragma unroll
      for (int n = 0; n < 4; ++n)
#pragma unroll
        for (int r = 0; r < 4; ++r)
          if (kb0 + n * 16 + r > qrow) s[n][r] = -1e30f;
    }
    // P = exp2(S) (static shift: |arg| <= 11.08 after RMSNorm); lane-partial sum
    float psum = 0.f;
#pragma unroll
    for (int n = 0; n < 4; ++n) {
      float p0 = exp2f(s[n][0]), p1 = exp2f(s[n][1]);
      float p2 = exp2f(s[n][2]), p3 = exp2f(s[n][3]);
      psum += (p0 + p1) + (p2 + p3);
      uint2 w;
      w.x = pk2(p0, p1);
      w.y = pk2(p2, p3);
      *(uint2*)&Plds[wid][lr][n * 16 + lg * 4] = w;
    }
    lrow += psum;
    // PV: O^T += V^T . P^T
#pragma unroll
    for (int kk = 0; kk < 2; ++kk) {
      bf16x8 ap = *(const bf16x8*)&Plds[wid][lr][kk * 32 + lg * 8];
#pragma unroll
      for (int n = 0; n < 4; ++n) {
        bf16x8 vf = *(const bf16x8*)&Vc[(n * 16 + lr) * HDIM + fcol[kk]];
        o[n] = __builtin_amdgcn_mfma_f32_16x16x32_bf16(vf, ap, o[n], 0, 0, 0);
      }
    }
    __syncthreads();  // staging landed (vmcnt 0) + buf[cur] consumed by all
  }
  // epilogue: complete row sum across lg groups, normalize, write
  lrow += __shfl_xor(lrow, 16);
  lrow += __shfl_xor(lrow, 32);
  float inv = 1.0f / lrow;
  int row = r0 + lr;
#pragma unroll
  for (int n = 0; n < 4; ++n) {
    uint2 w;
    w.x = pk2(o[n][0] * inv, o[n][1] * inv);
    w.y = pk2(o[n][2] * inv, o[n][3] * inv);
    *(uint2*)&Y[((size_t)b * T_SEQ + row) * DIMSZ + h * HDIM + n * 16 + lg * 4] = w;
  }
}

// ---------------- launch ----------------
extern "C" void kernel_launch(void* const* d_in, const int* in_sizes, int n_in,
                              void* d_out, int out_size, void* d_ws, size_t ws_size,
                              hipStream_t stream) {
  const float* x   = (const float*)d_in[0];
  const float* ve  = (const float*)d_in[1];
  const float* lam = (const float*)d_in[2];
  const float* w   = (const float*)d_in[4];  // (4, 1024, 1024)
  float* out = (float*)d_out;

  char* ws = (char*)d_ws;
  const size_t NTOK = (size_t)NBATCH * T_SEQ;          // 4096
  const size_t nX = NTOK * DIMSZ;                      // 4,194,304
  const size_t nW = 4ull * DIMSZ * DIMSZ;              // 4,194,304

  ushort* Xb   = (ushort*)(ws);                        // 8 MB  @ 0
  ushort* Wb   = (ushort*)(ws + 8388608);              // 8 MB  @ 8M
  ushort* Qb   = (ushort*)(ws + 16777216);             // 8 MB  @ 16M
  ushort* Kb   = (ushort*)(ws + 25165824);             // 8 MB  @ 24M
  ushort* Vt   = (ushort*)(ws + 33554432);             // 8 MB  @ 32M
  ushort* Yb   = (ushort*)(ws + 41943040);             // 8 MB  @ 40M
  float*  ctab = (float*)(ws + 50331648);              // 256 KB @ 48M
  float*  stab = (float*)(ws + 50593792);              // 256 KB

  conv_bf16_k<<<(int)(nX / 4 / 256), 256, 0, stream>>>(x, Xb, (int)nX);
  conv_bf16_k<<<(int)(nW / 4 / 256), 256, 0, stream>>>(w, Wb, (int)nW);
  rope_tab_k<<<(T_SEQ * 32) / 256, 256, 0, stream>>>(ctab, stab);

  // QKV GEMM (4096 x 3072 x 1024), 128^2 single-buffer + swizzle, fused epilogue
  gemm_qkv_k<<<dim3(4096 / BM, 3072 / BN), 256, 0, stream>>>(Xb, Wb, ve, lam, ctab, stab,
                                                             Qb, Kb, Vt);

  // attention v3: one q-tile per block, heavy-first, 3 blocks/CU
  attn_k<<<dim3(NBATCH * NH, 32), 256, 0, stream>>>(Qb, Kb, Vt, Yb);

  // out-proj: (4096 x 1024) = Yb @ W3^T, 64x128 tiles (512 blocks, 2/CU)
  gemm_out_k<<<dim3(4096 / 64, 1024 / 128), 256, 0, stream>>>(Yb, Wb + 3ull * DIMSZ * DIMSZ, out);
}